// Round 7
// baseline (1722.519 us; speedup 1.0000x reference)
//
#include <hip/hip_runtime.h>

// Round 7: r6 PASSED (1695 us, absmax 0.0039). Counters: knn<64> = 685 us x2
// (81%), VALUBusy 54%, occupancy 23% (1 blk/CU), HBM 1%. LDS-stall-bound.
// This round: phase A -> 8x8 register tiles via 2-way c-split (halves LDS
// instr, row-frags become broadcasts) + strided col pairs (4-way bank
// conflict -> 2-way = free). dist partials combined via group-1 RMW pass.
// Phase B / merge / prep / gather unchanged (accuracy-neutral rework).

#define NPTS 4096
#define NB 8
#define KK 20

// ---------------------------------------------------------------------------
// sorted-descending top-K insertion, all-static indexing (registers, no scratch)
// caller guarantees v > tv[KK-1]; stable (strict >) so earlier-inserted
// (= lower global index, given ascending-index call order) wins ties.
// ---------------------------------------------------------------------------
__device__ __forceinline__ void topk_insert(float v, int gi, float (&tv)[KK], int (&ti)[KK]) {
#pragma unroll
    for (int j = KK - 1; j >= 1; --j) {
        if (v > tv[j - 1])      { tv[j] = tv[j - 1]; ti[j] = ti[j - 1]; }
        else if (v > tv[j])     { tv[j] = v;         ti[j] = gi; }
    }
    if (v > tv[0]) { tv[0] = v; ti[0] = gi; }
}

// ---------------------------------------------------------------------------
// prep: per layer, computes
//   Z[b,n,o]  = (W1[o]·x_n) * inv[o]          (BN scale folded)
//   T[b,n,o]  = ((W2-W1)[o]·x_n + bias) * inv + (beta - mean*inv)
// so a neighbor candidate value is simply Z[m,o] + T[n,o].
// ---------------------------------------------------------------------------
template <int C, int CO>
__global__ __launch_bounds__(256) void prep_kernel(
    const float* __restrict__ x, const float* __restrict__ W,
    const float* __restrict__ bias, const float* __restrict__ gam,
    const float* __restrict__ bet, const float* __restrict__ mean,
    const float* __restrict__ var,
    float* __restrict__ Z, float* __restrict__ T)
{
    constexpr int OS = CO / 16;  // o's per thread (stride-16 interleave)
    __shared__ float xs[C][64];
    __shared__ float w1s[C][CO];
    __shared__ float wds[C][CO];
    const int tid = threadIdx.x;
    const int b  = blockIdx.y;
    const int n0 = blockIdx.x * 64;

    for (int i = tid; i < C * 64; i += 256)
        xs[i >> 6][i & 63] = x[((size_t)b * C + (i >> 6)) * NPTS + n0 + (i & 63)];
    for (int i = tid; i < C * CO; i += 256) {
        const int c = i / CO, o = i - c * CO;
        const float w1 = W[o * (2 * C) + c];
        const float w2 = W[o * (2 * C) + C + c];
        w1s[c][o] = w1;
        wds[c][o] = w2 - w1;
    }
    __syncthreads();

    const int to = tid & 15, tn = tid >> 4;
    float az[4][OS], at[4][OS];
#pragma unroll
    for (int i = 0; i < 4; ++i)
#pragma unroll
        for (int j = 0; j < OS; ++j) { az[i][j] = 0.f; at[i][j] = 0.f; }

#pragma unroll 4
    for (int c = 0; c < C; ++c) {
        float xv[4];
#pragma unroll
        for (int i = 0; i < 4; ++i) xv[i] = xs[c][tn * 4 + i];
#pragma unroll
        for (int j = 0; j < OS; ++j) {
            const float a1 = w1s[c][j * 16 + to];
            const float ad = wds[c][j * 16 + to];
#pragma unroll
            for (int i = 0; i < 4; ++i) { az[i][j] += a1 * xv[i]; at[i][j] += ad * xv[i]; }
        }
    }

#pragma unroll
    for (int j = 0; j < OS; ++j) {
        const int o = j * 16 + to;
        const float inv = gam[o] / sqrtf(var[o] + 1e-5f);
        const float sh  = bet[o] - mean[o] * inv;
        const float bo  = bias[o];
#pragma unroll
        for (int i = 0; i < 4; ++i) {
            const int n = n0 + tn * 4 + i;
            const size_t base = ((size_t)b * NPTS + n) * CO + o;
            Z[base] = az[i][j] * inv;
            T[base] = (at[i][j] + bo) * inv + sh;
        }
    }
}

// ---------------------------------------------------------------------------
// knn: fused distance + exact top-20. 512 threads (8 waves -> 2/SIMD).
// Block owns 128 rows of one batch. Per 128-col tile:
//   phase A: 2 c-groups x 256 threads, 8x8 register tiles over the SAME
//            128x128 output tile (each group accumulates half the channels).
//            Row-frag reads are wave-broadcast (free); col-frags are two
//            strided b128 pairs (tc8*4, 64+tc8*4) -> 2-way banks (free).
//            s = -sum_c (a-b)^2 exactly as r6 (no cancellation).
//            Group0 writes +partial to dist; group1 RMW-adds its partial
//            and negates. Next tile's colX prefetched global->reg.
//   phase B: 4 lanes/row x 32 cols; bank-rotated scan -> accept mask at
//            true columns -> ascending-index clustered inserts (jax ties).
// End: exact 4-way merge per row, value-desc with INDEX tie-break (jax).
// ---------------------------------------------------------------------------
template <int C>
__global__ __launch_bounds__(512) void knn_kernel(
    const float* __restrict__ x, int* __restrict__ nbr)
{
    constexpr int DP = 132;                          // 128 cols + 4 pad
    constexpr int MAIN  = 2 * C * 128 + 128 * DP;    // C=64: 33280 fl = 130 KiB
    constexpr int MERGE = 2 * 128 * 85;              // mv + mi, 4 slots * 21 pad
    constexpr int SW = (MAIN > MERGE) ? MAIN : MERGE;
    constexpr int NPF = (C * 128 + 2047) / 2048;     // float4 prefetch chunks/thread
    constexpr int CH = (C + 1) / 2;                  // c-split point
    __shared__ __align__(16) float smem[SW];
    float* rowX = smem;
    float* colX = smem + C * 128;
    float* dist = smem + 2 * C * 128;

    const int tid = threadIdx.x;
    const int b  = blockIdx.y;
    const int n0 = blockIdx.x * 128;
    const int cs  = tid >> 8;                        // c-group 0/1
    const int t2  = tid & 255;
    const int tr8 = t2 >> 4;                         // row block 0..15 (8 rows)
    const int tc8 = t2 & 15;                         // col block 0..15 (4+4 cols)
    const int prow = tid >> 2, pslot = tid & 3;      // phase B mapping
    const float* xb = x + (size_t)b * C * NPTS;

    float tkv[KK]; int tki[KK];
#pragma unroll
    for (int j = 0; j < KK; ++j) { tkv[j] = -3.0e38f; tki[j] = 0; }

    // rowX: this block's 128 query rows (loaded once)
    for (int i = tid * 4; i < C * 128; i += 2048)
        *(float4*)&rowX[i] = *(const float4*)&xb[(size_t)(i >> 7) * NPTS + n0 + (i & 127)];

    // prefetch tile 0 colX into registers
    float4 pf[NPF];
#pragma unroll
    for (int u = 0; u < NPF; ++u) {
        const int i = tid * 4 + u * 2048;
        if (i < C * 128) pf[u] = *(const float4*)&xb[(size_t)(i >> 7) * NPTS + (i & 127)];
    }

    const int c0   = cs ? CH : 0;          // this group's channel range
    const int trip = cs ? (C - CH) : CH;
    const float* rA = rowX + (size_t)c0 * 128 + tr8 * 8;
    const float* cB = colX + (size_t)c0 * 128 + tc8 * 4;

    for (int t = 0; t < NPTS / 128; ++t) {
        const int m0 = t * 128;
        const int m0n = (m0 + 128) & (NPTS - 1);     // wrapped: t=31 load unused
        __syncthreads();                              // prev phase B done
        // commit prefetched colX
#pragma unroll
        for (int u = 0; u < NPF; ++u) {
            const int i = tid * 4 + u * 2048;
            if (i < C * 128) *(float4*)&colX[i] = pf[u];
        }
        // issue next tile's loads (in flight across phases A+B)
#pragma unroll
        for (int u = 0; u < NPF; ++u) {
            const int i = tid * 4 + u * 2048;
            if (i < C * 128) pf[u] = *(const float4*)&xb[(size_t)(i >> 7) * NPTS + m0n + (i & 127)];
        }
        __syncthreads();

        // phase A: 8 rows x (4+4) cols per thread, partial d^2 over trip c's
        float acc[8][8];
#pragma unroll
        for (int i = 0; i < 8; ++i)
#pragma unroll
            for (int j = 0; j < 8; ++j) acc[i][j] = 0.f;

#pragma unroll 2
        for (int k = 0; k < trip; ++k) {
            const float4 a0 = *(const float4*)&rA[k * 128];
            const float4 a1 = *(const float4*)&rA[k * 128 + 4];
            const float4 b0 = *(const float4*)&cB[k * 128];
            const float4 b1 = *(const float4*)&cB[k * 128 + 64];
            const float av[8] = {a0.x, a0.y, a0.z, a0.w, a1.x, a1.y, a1.z, a1.w};
            const float bv[8] = {b0.x, b0.y, b0.z, b0.w, b1.x, b1.y, b1.z, b1.w};
#pragma unroll
            for (int i = 0; i < 8; ++i)
#pragma unroll
                for (int j = 0; j < 8; ++j) {
                    const float d = av[i] - bv[j];
                    acc[i][j] += d * d;
                }
        }

        if (cs == 0) {      // group0: write +partial
#pragma unroll
            for (int i = 0; i < 8; ++i) {
                const int r = tr8 * 8 + i;
                float4 w0, w1;
                w0.x = acc[i][0]; w0.y = acc[i][1]; w0.z = acc[i][2]; w0.w = acc[i][3];
                w1.x = acc[i][4]; w1.y = acc[i][5]; w1.z = acc[i][6]; w1.w = acc[i][7];
                *(float4*)&dist[r * DP + tc8 * 4]      = w0;
                *(float4*)&dist[r * DP + 64 + tc8 * 4] = w1;
            }
        }
        __syncthreads();
        if (cs == 1) {      // group1: RMW-add partial, negate -> final score
#pragma unroll
            for (int i = 0; i < 8; ++i) {
                const int r = tr8 * 8 + i;
                float4 p0 = *(const float4*)&dist[r * DP + tc8 * 4];
                float4 p1 = *(const float4*)&dist[r * DP + 64 + tc8 * 4];
                p0.x = -(p0.x + acc[i][0]); p0.y = -(p0.y + acc[i][1]);
                p0.z = -(p0.z + acc[i][2]); p0.w = -(p0.w + acc[i][3]);
                p1.x = -(p1.x + acc[i][4]); p1.y = -(p1.y + acc[i][5]);
                p1.z = -(p1.z + acc[i][6]); p1.w = -(p1.w + acc[i][7]);
                *(float4*)&dist[r * DP + tc8 * 4]      = p0;
                *(float4*)&dist[r * DP + 64 + tc8 * 4] = p1;
            }
        }
        __syncthreads();

        // phase B: bank-rotated scan; bit stored at TRUE column cc so the
        // insert loop processes ascending global index (jax tie-break).
        // bank = (5*prow + 8*pslot + jj) mod 32 -> ~2 lanes/bank (free).
        unsigned mask = 0u;
        const float thr = tkv[KK - 1];
        const float* drow = dist + prow * DP + pslot * 32;
        const int rot = (prow + 8 * pslot) & 31;
#pragma unroll
        for (int jj = 0; jj < 32; ++jj) {
            const int cc = (jj + rot) & 31;
            mask |= ((unsigned)(drow[cc] > thr)) << cc;
        }
        const int gb = m0 + pslot * 32;
        while (mask) {
            const int cc = __ffs(mask) - 1;
            mask &= mask - 1;
            const float v = drow[cc];
            if (v > tkv[KK - 1]) topk_insert(v, gb + cc, tkv, tki);
        }
    }
    __syncthreads();

    // dump 4 sorted lists per row (+ pad guard), exact 4-way merge with
    // value-desc / index-asc ordering (matches jax.lax.top_k exactly).
    float* mv = smem;                      // 128*85 floats
    int*   mi = (int*)(smem + 128 * 85);   // 128*85 ints
    const int mbase = prow * 85 + pslot * 21;
#pragma unroll
    for (int j = 0; j < KK; ++j) { mv[mbase + j] = tkv[j]; mi[mbase + j] = tki[j]; }
    mv[mbase + KK] = -3.0e38f;             // pad value: below any real score
    mi[mbase + KK] = 0x7fffffff;           // pad index: loses every index tie
    __syncthreads();
    if (tid < 128) {
        int* orow = nbr + ((size_t)b * NPTS + n0 + tid) * KK;
        const int rb = tid * 85;
        int p0 = rb, p1 = rb + 21, p2 = rb + 42, p3 = rb + 63;
        float v0 = mv[p0], v1 = mv[p1], v2 = mv[p2], v3 = mv[p3];
        int   i0 = mi[p0], i1 = mi[p1], i2 = mi[p2], i3 = mi[p3];
#pragma unroll 1
        for (int k = 0; k < KK; ++k) {
            float best = v0; int bi = i0; int bs = 0;
            if (v1 > best || (v1 == best && i1 < bi)) { best = v1; bi = i1; bs = 1; }
            if (v2 > best || (v2 == best && i2 < bi)) { best = v2; bi = i2; bs = 2; }
            if (v3 > best || (v3 == best && i3 < bi)) { best = v3; bi = i3; bs = 3; }
            orow[k] = bi;
            if (bs == 0)      { ++p0; v0 = mv[p0]; i0 = mi[p0]; }
            else if (bs == 1) { ++p1; v1 = mv[p1]; i1 = mi[p1]; }
            else if (bs == 2) { ++p2; v2 = mv[p2]; i2 = mi[p2]; }
            else              { ++p3; v3 = mv[p3]; i3 = mi[p3]; }
        }
    }
}

// ---------------------------------------------------------------------------
// gather: out[b,o,n] = max_k lrelu( Z[b,idx[n,k],o] + T[b,n,o] )
// ---------------------------------------------------------------------------
template <int CO>
__global__ __launch_bounds__(256) void gather_kernel(
    const float* __restrict__ Z, const float* __restrict__ T,
    const int* __restrict__ nbr, float* __restrict__ out)
{
    constexpr int CQ = CO / 4;
    __shared__ int idxl[64 * 21];
    const int tid = threadIdx.x;
    const int b  = blockIdx.y;
    const int n0 = blockIdx.x * 64;

    for (int i = tid; i < 64 * KK; i += 256) {
        const int n = i / KK, k2 = i - n * KK;
        idxl[n * 21 + k2] = nbr[((size_t)b * NPTS + n0) * KK + i];
    }
    __syncthreads();

    const int og = tid >> 6;   // whole wave shares og -> coalesced output
    const int ns = tid & 63;
    const float* Tb = T + ((size_t)b * NPTS + n0 + ns) * CO + og * CQ;
    float tv[CQ];
#pragma unroll
    for (int j = 0; j < CQ; j += 4) {
        const float4 q = *(const float4*)&Tb[j];
        tv[j] = q.x; tv[j + 1] = q.y; tv[j + 2] = q.z; tv[j + 3] = q.w;
    }
    float acc[CQ];
#pragma unroll
    for (int j = 0; j < CQ; ++j) acc[j] = -3.0e38f;

    const float* Zb = Z + (size_t)b * NPTS * CO + og * CQ;
#pragma unroll 1
    for (int k2 = 0; k2 < KK; ++k2) {
        const int m = idxl[ns * 21 + k2];
        const float* zr = Zb + (size_t)m * CO;
#pragma unroll
        for (int j = 0; j < CQ; j += 4) {
            const float4 z4 = *(const float4*)&zr[j];
            float v;
            v = z4.x + tv[j];     v = v > 0.f ? v : 0.2f * v; acc[j]     = fmaxf(acc[j], v);
            v = z4.y + tv[j + 1]; v = v > 0.f ? v : 0.2f * v; acc[j + 1] = fmaxf(acc[j + 1], v);
            v = z4.z + tv[j + 2]; v = v > 0.f ? v : 0.2f * v; acc[j + 2] = fmaxf(acc[j + 2], v);
            v = z4.w + tv[j + 3]; v = v > 0.f ? v : 0.2f * v; acc[j + 3] = fmaxf(acc[j + 3], v);
        }
    }
#pragma unroll
    for (int j = 0; j < CQ; ++j)
        out[((size_t)b * CO + og * CQ + j) * NPTS + n0 + ns] = acc[j];
}

// ---------------------------------------------------------------------------
extern "C" void kernel_launch(void* const* d_in, const int* in_sizes, int n_in,
                              void* d_out, int out_size, void* d_ws, size_t ws_size,
                              hipStream_t stream)
{
    const float* x0  = (const float*)d_in[0];
    const float* W0  = (const float*)d_in[1];
    const float* b0  = (const float*)d_in[2];
    const float* g0  = (const float*)d_in[3];
    const float* be0 = (const float*)d_in[4];
    const float* mn0 = (const float*)d_in[5];
    const float* vr0 = (const float*)d_in[6];
    const float* W1  = (const float*)d_in[7];
    const float* b1  = (const float*)d_in[8];
    const float* g1  = (const float*)d_in[9];
    const float* be1 = (const float*)d_in[10];
    const float* mn1 = (const float*)d_in[11];
    const float* vr1 = (const float*)d_in[12];
    const float* W2  = (const float*)d_in[13];
    const float* b2  = (const float*)d_in[14];
    const float* g2  = (const float*)d_in[15];
    const float* be2 = (const float*)d_in[16];
    const float* mn2 = (const float*)d_in[17];
    const float* vr2 = (const float*)d_in[18];

    // workspace layout (words): Z 4M | T 4M | nb 640K | xA 2M  ~= 44 MB
    float* ws = (float*)d_ws;
    float* Z  = ws;                                        // 8*4096*128 (max co)
    float* Tt = Z  + (size_t)NB * NPTS * 128;
    int*   nb = (int*)(Tt + (size_t)NB * NPTS * 128);      // 8*4096*20
    float* xA = (float*)(nb + (size_t)NB * NPTS * KK);     // 8*64*4096
    float* xB = xA;                                        // xA dead after layer-1 knn
    float* op = (float*)d_out;
    (void)in_sizes; (void)n_in; (void)out_size; (void)ws_size;

    const dim3 blk(256), blkK(512);
    const dim3 gP(64, NB), gKn(32, NB), gG(64, NB);

    // layer 0 (C=3 -> 64)
    prep_kernel<3, 64><<<gP, blk, 0, stream>>>(x0, W0, b0, g0, be0, mn0, vr0, Z, Tt);
    knn_kernel<3><<<gKn, blkK, 0, stream>>>(x0, nb);
    gather_kernel<64><<<gG, blk, 0, stream>>>(Z, Tt, nb, xA);

    // layer 1 (C=64 -> 64)
    prep_kernel<64, 64><<<gP, blk, 0, stream>>>(xA, W1, b1, g1, be1, mn1, vr1, Z, Tt);
    knn_kernel<64><<<gKn, blkK, 0, stream>>>(xA, nb);
    gather_kernel<64><<<gG, blk, 0, stream>>>(Z, Tt, nb, xB);

    // layer 2 (C=64 -> 128)
    prep_kernel<64, 128><<<gP, blk, 0, stream>>>(xB, W2, b2, g2, be2, mn2, vr2, Z, Tt);
    knn_kernel<64><<<gKn, blkK, 0, stream>>>(xB, nb);
    gather_kernel<128><<<gG, blk, 0, stream>>>(Z, Tt, nb, op);
}

// Round 10
// 1653.343 us; speedup vs baseline: 1.0418x; 1.0418x over previous
//
#include <hip/hip_runtime.h>

// Round 10: r8/r9 never ran (GPU acquisition timeouts). Resubmitting the
// audited design unchanged (3rd audit pass clean): (1) wave-staggered c-loop,
// (2) explicit float4-component FMAs + offset-folded addressing, (3) 2
// barriers/tile. Next successful bench attributes cleanly to this delta
// vs r6's 685 us knn<64>.

#define NPTS 4096
#define NB 8
#define KK 20

// ---------------------------------------------------------------------------
// sorted-descending top-K insertion, all-static indexing (registers, no scratch)
// caller guarantees v > tv[KK-1]; stable (strict >) so earlier-inserted
// (= lower global index, given ascending-index call order) wins ties.
// ---------------------------------------------------------------------------
__device__ __forceinline__ void topk_insert(float v, int gi, float (&tv)[KK], int (&ti)[KK]) {
#pragma unroll
    for (int j = KK - 1; j >= 1; --j) {
        if (v > tv[j - 1])      { tv[j] = tv[j - 1]; ti[j] = ti[j - 1]; }
        else if (v > tv[j])     { tv[j] = v;         ti[j] = gi; }
    }
    if (v > tv[0]) { tv[0] = v; ti[0] = gi; }
}

// ---------------------------------------------------------------------------
// prep: per layer, computes
//   Z[b,n,o]  = (W1[o]·x_n) * inv[o]          (BN scale folded)
//   T[b,n,o]  = ((W2-W1)[o]·x_n + bias) * inv + (beta - mean*inv)
// so a neighbor candidate value is simply Z[m,o] + T[n,o].
// ---------------------------------------------------------------------------
template <int C, int CO>
__global__ __launch_bounds__(256) void prep_kernel(
    const float* __restrict__ x, const float* __restrict__ W,
    const float* __restrict__ bias, const float* __restrict__ gam,
    const float* __restrict__ bet, const float* __restrict__ mean,
    const float* __restrict__ var,
    float* __restrict__ Z, float* __restrict__ T)
{
    constexpr int OS = CO / 16;  // o's per thread (stride-16 interleave)
    __shared__ float xs[C][64];
    __shared__ float w1s[C][CO];
    __shared__ float wds[C][CO];
    const int tid = threadIdx.x;
    const int b  = blockIdx.y;
    const int n0 = blockIdx.x * 64;

    for (int i = tid; i < C * 64; i += 256)
        xs[i >> 6][i & 63] = x[((size_t)b * C + (i >> 6)) * NPTS + n0 + (i & 63)];
    for (int i = tid; i < C * CO; i += 256) {
        const int c = i / CO, o = i - c * CO;
        const float w1 = W[o * (2 * C) + c];
        const float w2 = W[o * (2 * C) + C + c];
        w1s[c][o] = w1;
        wds[c][o] = w2 - w1;
    }
    __syncthreads();

    const int to = tid & 15, tn = tid >> 4;
    float az[4][OS], at[4][OS];
#pragma unroll
    for (int i = 0; i < 4; ++i)
#pragma unroll
        for (int j = 0; j < OS; ++j) { az[i][j] = 0.f; at[i][j] = 0.f; }

#pragma unroll 4
    for (int c = 0; c < C; ++c) {
        float xv[4];
#pragma unroll
        for (int i = 0; i < 4; ++i) xv[i] = xs[c][tn * 4 + i];
#pragma unroll
        for (int j = 0; j < OS; ++j) {
            const float a1 = w1s[c][j * 16 + to];
            const float ad = wds[c][j * 16 + to];
#pragma unroll
            for (int i = 0; i < 4; ++i) { az[i][j] += a1 * xv[i]; at[i][j] += ad * xv[i]; }
        }
    }

#pragma unroll
    for (int j = 0; j < OS; ++j) {
        const int o = j * 16 + to;
        const float inv = gam[o] / sqrtf(var[o] + 1e-5f);
        const float sh  = bet[o] - mean[o] * inv;
        const float bo  = bias[o];
#pragma unroll
        for (int i = 0; i < 4; ++i) {
            const int n = n0 + tn * 4 + i;
            const size_t base = ((size_t)b * NPTS + n) * CO + o;
            Z[base] = az[i][j] * inv;
            T[base] = (at[i][j] + bo) * inv + sh;
        }
    }
}

// 8 rows x 4 cols d^2 accumulation step, fully explicit (no staging arrays)
#define FROW(i, aval)                                                         \
    { const float a_ = (aval);                                                \
      const float d0_ = a_ - b0, d1_ = a_ - b1, d2_ = a_ - b2, d3_ = a_ - b3; \
      acc[i][0] += d0_ * d0_; acc[i][1] += d1_ * d1_;                         \
      acc[i][2] += d2_ * d2_; acc[i][3] += d3_ * d3_; }

#define FSTEP()                                                               \
    { const float4 a0 = *(const float4*)pA;                                   \
      const float4 a1 = *(const float4*)(pA + 4);                             \
      const float4 b4 = *(const float4*)pB;                                   \
      pA += 128; pB += 128;                                                   \
      const float b0 = b4.x, b1 = b4.y, b2 = b4.z, b3 = b4.w;                 \
      FROW(0, a0.x) FROW(1, a0.y) FROW(2, a0.z) FROW(3, a0.w)                 \
      FROW(4, a1.x) FROW(5, a1.y) FROW(6, a1.z) FROW(7, a1.w) }

// ---------------------------------------------------------------------------
// knn: fused distance + exact top-20. 512 threads (8 waves -> 2/SIMD; LDS
// caps us at 1 block/CU anyway).
// Block owns 128 rows of one batch. Per 128-col tile:
//   phase A: 8x4 register-tiled s = -sum_c (a-b)^2 (cancellation-free, r6);
//            WAVE-STAGGERED c order (wave w sums c = 8w..63, 0..8w-1) so one
//            wave's LDS batch overlaps another's FMA batch. Per-row order
//            stays consistent (each row owned by one wave); d^2 sums are
//            order-tolerant (~1e-7 rel; r6 margin 24x).
//   phase B: 4 lanes/row x 32 cols; bank-rotated scan -> accept mask at
//            true columns -> ascending-index clustered inserts (jax ties).
// End: exact 4-way merge per row, value-desc with INDEX tie-break (jax).
// ---------------------------------------------------------------------------
template <int C>
__global__ __launch_bounds__(512) void knn_kernel(
    const float* __restrict__ x, int* __restrict__ nbr)
{
    constexpr int DP = 132;                          // 128 cols + 4 pad
    constexpr int MAIN  = 2 * C * 128 + 128 * DP;    // C=64: 33280 fl = 130 KiB
    constexpr int MERGE = 2 * 128 * 85;              // mv + mi, 4 slots * 21 pad
    constexpr int SW = (MAIN > MERGE) ? MAIN : MERGE;
    constexpr int NPF = (C * 128 + 2047) / 2048;     // float4 prefetch chunks/thread
    __shared__ __align__(16) float smem[SW];
    float* rowX = smem;
    float* colX = smem + C * 128;
    float* dist = smem + 2 * C * 128;

    const int tid = threadIdx.x;
    const int b  = blockIdx.y;
    const int n0 = blockIdx.x * 128;
    const int tc = tid & 31, tr = tid >> 5;          // phase A: 16x32 threads, 8x4 regs
    const int prow = tid >> 2, pslot = tid & 3;      // phase B: 4 lanes/row, 32 cols
    const float* xb = x + (size_t)b * C * NPTS;

    float tkv[KK]; int tki[KK];
#pragma unroll
    for (int j = 0; j < KK; ++j) { tkv[j] = -3.0e38f; tki[j] = 0; }

    // rowX: this block's 128 query rows (loaded once)
    for (int i = tid * 4; i < C * 128; i += 2048)
        *(float4*)&rowX[i] = *(const float4*)&xb[(size_t)(i >> 7) * NPTS + n0 + (i & 127)];

    // prefetch tile 0 colX into registers
    float4 pf[NPF];
#pragma unroll
    for (int u = 0; u < NPF; ++u) {
        const int i = tid * 4 + u * 2048;
        if (i < C * 128) pf[u] = *(const float4*)&xb[(size_t)(i >> 7) * NPTS + (i & 127)];
    }

    // wave-staggered channel start (C=64 path): wave w begins at c0 = 8w
    const int c0 = (C == 64) ? ((tid >> 6) * 8) : 0;
    const float* rA0 = rowX + tr * 8;
    const float* cB0 = colX + tc * 4;

    for (int t = 0; t < NPTS / 128; ++t) {
        const int m0 = t * 128;
        const int m0n = (m0 + 128) & (NPTS - 1);     // wrapped: t=31 load unused
        // (no barrier here: BAR_B below already fences colX writes vs reads)
        // commit prefetched colX
#pragma unroll
        for (int u = 0; u < NPF; ++u) {
            const int i = tid * 4 + u * 2048;
            if (i < C * 128) *(float4*)&colX[i] = pf[u];
        }
        // issue next tile's loads (in flight across phases A+B)
#pragma unroll
        for (int u = 0; u < NPF; ++u) {
            const int i = tid * 4 + u * 2048;
            if (i < C * 128) pf[u] = *(const float4*)&xb[(size_t)(i >> 7) * NPTS + m0n + (i & 127)];
        }
        __syncthreads();                              // BAR_A: colX ready

        // phase A: 8 rows x 4 cols per thread, s = sum_c (a-b)^2
        float acc[8][4];
#pragma unroll
        for (int i = 0; i < 8; ++i)
#pragma unroll
            for (int j = 0; j < 4; ++j) acc[i][j] = 0.f;

        if (C == 64) {
            // segment 1: c = c0 .. 63
            {
                const float* pA = rA0 + c0 * 128;
                const float* pB = cB0 + c0 * 128;
#pragma unroll 4
                for (int k = c0; k < 64; ++k) FSTEP()
            }
            // segment 2: c = 0 .. c0-1
            {
                const float* pA = rA0;
                const float* pB = cB0;
#pragma unroll 4
                for (int k = 0; k < c0; ++k) FSTEP()
            }
        } else {
            const float* pA = rA0;
            const float* pB = cB0;
#pragma unroll
            for (int k = 0; k < C; ++k) FSTEP()
        }

#pragma unroll
        for (int i = 0; i < 8; ++i) {
            const int r = tr * 8 + i;
            float4 w;   // score = -d^2 (monotone-equal to 2ab-aa-bb ordering)
            w.x = -acc[i][0];
            w.y = -acc[i][1];
            w.z = -acc[i][2];
            w.w = -acc[i][3];
            *(float4*)&dist[r * DP + tc * 4] = w;
        }
        __syncthreads();                              // BAR_B: dist ready

        // phase B: bank-rotated scan; bit stored at TRUE column cc so the
        // insert loop processes ascending global index (jax tie-break).
        // bank = (5*prow + 8*pslot + jj) mod 32 -> ~2 lanes/bank (free).
        unsigned mask = 0u;
        const float thr = tkv[KK - 1];
        const float* drow = dist + prow * DP + pslot * 32;
        const int rot = (prow + 8 * pslot) & 31;
#pragma unroll
        for (int jj = 0; jj < 32; ++jj) {
            const int cc = (jj + rot) & 31;
            mask |= ((unsigned)(drow[cc] > thr)) << cc;
        }
        const int gb = m0 + pslot * 32;
        while (mask) {
            const int cc = __ffs(mask) - 1;
            mask &= mask - 1;
            const float v = drow[cc];
            if (v > tkv[KK - 1]) topk_insert(v, gb + cc, tkv, tki);
        }
    }
    __syncthreads();

    // dump 4 sorted lists per row (+ pad guard), exact 4-way merge with
    // value-desc / index-asc ordering (matches jax.lax.top_k exactly).
    float* mv = smem;                      // 128*85 floats
    int*   mi = (int*)(smem + 128 * 85);   // 128*85 ints
    const int mbase = prow * 85 + pslot * 21;
#pragma unroll
    for (int j = 0; j < KK; ++j) { mv[mbase + j] = tkv[j]; mi[mbase + j] = tki[j]; }
    mv[mbase + KK] = -3.0e38f;             // pad value: below any real score
    mi[mbase + KK] = 0x7fffffff;           // pad index: loses every index tie
    __syncthreads();
    if (tid < 128) {
        int* orow = nbr + ((size_t)b * NPTS + n0 + tid) * KK;
        const int rb = tid * 85;
        int p0 = rb, p1 = rb + 21, p2 = rb + 42, p3 = rb + 63;
        float v0 = mv[p0], v1 = mv[p1], v2 = mv[p2], v3 = mv[p3];
        int   i0 = mi[p0], i1 = mi[p1], i2 = mi[p2], i3 = mi[p3];
#pragma unroll 1
        for (int k = 0; k < KK; ++k) {
            float best = v0; int bi = i0; int bs = 0;
            if (v1 > best || (v1 == best && i1 < bi)) { best = v1; bi = i1; bs = 1; }
            if (v2 > best || (v2 == best && i2 < bi)) { best = v2; bi = i2; bs = 2; }
            if (v3 > best || (v3 == best && i3 < bi)) { best = v3; bi = i3; bs = 3; }
            orow[k] = bi;
            if (bs == 0)      { ++p0; v0 = mv[p0]; i0 = mi[p0]; }
            else if (bs == 1) { ++p1; v1 = mv[p1]; i1 = mi[p1]; }
            else if (bs == 2) { ++p2; v2 = mv[p2]; i2 = mi[p2]; }
            else              { ++p3; v3 = mv[p3]; i3 = mi[p3]; }
        }
    }
}

// ---------------------------------------------------------------------------
// gather: out[b,o,n] = max_k lrelu( Z[b,idx[n,k],o] + T[b,n,o] )
// ---------------------------------------------------------------------------
template <int CO>
__global__ __launch_bounds__(256) void gather_kernel(
    const float* __restrict__ Z, const float* __restrict__ T,
    const int* __restrict__ nbr, float* __restrict__ out)
{
    constexpr int CQ = CO / 4;
    __shared__ int idxl[64 * 21];
    const int tid = threadIdx.x;
    const int b  = blockIdx.y;
    const int n0 = blockIdx.x * 64;

    for (int i = tid; i < 64 * KK; i += 256) {
        const int n = i / KK, k2 = i - n * KK;
        idxl[n * 21 + k2] = nbr[((size_t)b * NPTS + n0) * KK + i];
    }
    __syncthreads();

    const int og = tid >> 6;   // whole wave shares og -> coalesced output
    const int ns = tid & 63;
    const float* Tb = T + ((size_t)b * NPTS + n0 + ns) * CO + og * CQ;
    float tv[CQ];
#pragma unroll
    for (int j = 0; j < CQ; j += 4) {
        const float4 q = *(const float4*)&Tb[j];
        tv[j] = q.x; tv[j + 1] = q.y; tv[j + 2] = q.z; tv[j + 3] = q.w;
    }
    float acc[CQ];
#pragma unroll
    for (int j = 0; j < CQ; ++j) acc[j] = -3.0e38f;

    const float* Zb = Z + (size_t)b * NPTS * CO + og * CQ;
#pragma unroll 1
    for (int k2 = 0; k2 < KK; ++k2) {
        const int m = idxl[ns * 21 + k2];
        const float* zr = Zb + (size_t)m * CO;
#pragma unroll
        for (int j = 0; j < CQ; j += 4) {
            const float4 z4 = *(const float4*)&zr[j];
            float v;
            v = z4.x + tv[j];     v = v > 0.f ? v : 0.2f * v; acc[j]     = fmaxf(acc[j], v);
            v = z4.y + tv[j + 1]; v = v > 0.f ? v : 0.2f * v; acc[j + 1] = fmaxf(acc[j + 1], v);
            v = z4.z + tv[j + 2]; v = v > 0.f ? v : 0.2f * v; acc[j + 2] = fmaxf(acc[j + 2], v);
            v = z4.w + tv[j + 3]; v = v > 0.f ? v : 0.2f * v; acc[j + 3] = fmaxf(acc[j + 3], v);
        }
    }
#pragma unroll
    for (int j = 0; j < CQ; ++j)
        out[((size_t)b * CO + og * CQ + j) * NPTS + n0 + ns] = acc[j];
}

// ---------------------------------------------------------------------------
extern "C" void kernel_launch(void* const* d_in, const int* in_sizes, int n_in,
                              void* d_out, int out_size, void* d_ws, size_t ws_size,
                              hipStream_t stream)
{
    const float* x0  = (const float*)d_in[0];
    const float* W0  = (const float*)d_in[1];
    const float* b0  = (const float*)d_in[2];
    const float* g0  = (const float*)d_in[3];
    const float* be0 = (const float*)d_in[4];
    const float* mn0 = (const float*)d_in[5];
    const float* vr0 = (const float*)d_in[6];
    const float* W1  = (const float*)d_in[7];
    const float* b1  = (const float*)d_in[8];
    const float* g1  = (const float*)d_in[9];
    const float* be1 = (const float*)d_in[10];
    const float* mn1 = (const float*)d_in[11];
    const float* vr1 = (const float*)d_in[12];
    const float* W2  = (const float*)d_in[13];
    const float* b2  = (const float*)d_in[14];
    const float* g2  = (const float*)d_in[15];
    const float* be2 = (const float*)d_in[16];
    const float* mn2 = (const float*)d_in[17];
    const float* vr2 = (const float*)d_in[18];

    // workspace layout (words): Z 4M | T 4M | nb 640K | xA 2M  ~= 44 MB
    float* ws = (float*)d_ws;
    float* Z  = ws;                                        // 8*4096*128 (max co)
    float* Tt = Z  + (size_t)NB * NPTS * 128;
    int*   nb = (int*)(Tt + (size_t)NB * NPTS * 128);      // 8*4096*20
    float* xA = (float*)(nb + (size_t)NB * NPTS * KK);     // 8*64*4096
    float* xB = xA;                                        // xA dead after layer-1 knn
    float* op = (float*)d_out;
    (void)in_sizes; (void)n_in; (void)out_size; (void)ws_size;

    const dim3 blk(256), blkK(512);
    const dim3 gP(64, NB), gKn(32, NB), gG(64, NB);

    // layer 0 (C=3 -> 64)
    prep_kernel<3, 64><<<gP, blk, 0, stream>>>(x0, W0, b0, g0, be0, mn0, vr0, Z, Tt);
    knn_kernel<3><<<gKn, blkK, 0, stream>>>(x0, nb);
    gather_kernel<64><<<gG, blk, 0, stream>>>(Z, Tt, nb, xA);

    // layer 1 (C=64 -> 64)
    prep_kernel<64, 64><<<gP, blk, 0, stream>>>(xA, W1, b1, g1, be1, mn1, vr1, Z, Tt);
    knn_kernel<64><<<gKn, blkK, 0, stream>>>(xA, nb);
    gather_kernel<64><<<gG, blk, 0, stream>>>(Z, Tt, nb, xB);

    // layer 2 (C=64 -> 128)
    prep_kernel<64, 128><<<gP, blk, 0, stream>>>(xB, W2, b2, g2, be2, mn2, vr2, Z, Tt);
    knn_kernel<64><<<gKn, blkK, 0, stream>>>(xB, nb);
    gather_kernel<128><<<gG, blk, 0, stream>>>(Z, Tt, nb, op);
}